// Round 1
// baseline (341.768 us; speedup 1.0000x reference)
//
#include <hip/hip_runtime.h>
#include <hip/hip_bf16.h>
#include <stdint.h>

typedef __bf16 bf16x8 __attribute__((ext_vector_type(8)));
typedef float f32x4 __attribute__((ext_vector_type(4)));
typedef float f32x4v __attribute__((ext_vector_type(4)));
typedef unsigned short u16;
typedef unsigned int u32;
typedef u16 u16x8 __attribute__((ext_vector_type(8)));

#define B_ 2
#define S_ 2048
#define HID_ 2048
#define H_ 16
#define HK_ 4
#define D_ 128
#define NQKV_ 3072

__device__ __forceinline__ u16 f2bf(float f) {
  u32 u = __builtin_bit_cast(u32, f);
  u32 r = (u + 0x7fffu + ((u >> 16) & 1u)) >> 16;
  return (u16)r;
}

__device__ __forceinline__ void gload_lds16(const void* g, void* l) {
  __builtin_amdgcn_global_load_lds((const __attribute__((address_space(1))) void*)g,
                                   (__attribute__((address_space(3))) void*)l, 16, 0, 0);
}

// ---------------- f32 -> bf16 bulk convert ----------------
__global__ __launch_bounds__(256) void k_f32_to_bf16(const float* __restrict__ in,
                                                     u16* __restrict__ out, int n8) {
  for (int i = blockIdx.x * 256 + threadIdx.x; i < n8; i += gridDim.x * 256) {
    const f32x4v* p = (const f32x4v*)(in + (size_t)i * 8);
    f32x4v a = p[0], b = p[1];
    u16x8 w;
    w[0] = f2bf(a[0]); w[1] = f2bf(a[1]); w[2] = f2bf(a[2]); w[3] = f2bf(a[3]);
    w[4] = f2bf(b[0]); w[5] = f2bf(b[1]); w[6] = f2bf(b[2]); w[7] = f2bf(b[3]);
    *(u16x8*)(out + (size_t)i * 8) = w;
  }
}

// ---------------- bf16 GEMM: C[M][N] = A[M][K] * B[N][K]^T + bias ----------------
// 128x128 tile, BK=32, 4 waves (2x2), each wave 64x64 via 4x4 16x16x32 MFMA frags.
__global__ __launch_bounds__(256) void k_gemm_bt(const u16* __restrict__ A, const u16* __restrict__ Bm,
                                                 const float* __restrict__ bias, float* __restrict__ C,
                                                 int M, int N, int K) {
  __shared__ __attribute__((aligned(16))) u16 lA[128 * 32];
  __shared__ __attribute__((aligned(16))) u16 lB[128 * 32];
  const int tid = threadIdx.x;
  const int lane = tid & 63, wid = tid >> 6;
  const int wr = wid >> 1, wc = wid & 1;
  const int row0 = blockIdx.y * 128, col0 = blockIdx.x * 128;
  const int l15 = lane & 15, l4 = lane >> 4;
  f32x4 acc[4][4] = {};

  for (int k0 = 0; k0 < K; k0 += 32) {
#pragma unroll
    for (int iss = 0; iss < 2; ++iss) {
      int ob_w = wid * 2048 + iss * 1024;   // wave-uniform LDS byte base
      int ob = ob_w + lane * 16;            // this lane's byte offset within tile
      int r = ob >> 6, cb = ob & 63;
      gload_lds16((const char*)A + ((size_t)(row0 + r) * K + k0) * 2 + cb, (char*)lA + ob_w);
      gload_lds16((const char*)Bm + ((size_t)(col0 + r) * K + k0) * 2 + cb, (char*)lB + ob_w);
    }
    __syncthreads();
    bf16x8 af[4], bf[4];
#pragma unroll
    for (int m = 0; m < 4; ++m) af[m] = *(const bf16x8*)&lA[(wr * 64 + m * 16 + l15) * 32 + l4 * 8];
#pragma unroll
    for (int n = 0; n < 4; ++n) bf[n] = *(const bf16x8*)&lB[(wc * 64 + n * 16 + l15) * 32 + l4 * 8];
#pragma unroll
    for (int m = 0; m < 4; ++m)
#pragma unroll
      for (int n = 0; n < 4; ++n)
        acc[m][n] = __builtin_amdgcn_mfma_f32_16x16x32_bf16(af[m], bf[n], acc[m][n], 0, 0, 0);
    __syncthreads();
  }
#pragma unroll
  for (int m = 0; m < 4; ++m) {
    int grow_b = row0 + wr * 64 + m * 16 + l4 * 4;
#pragma unroll
    for (int n = 0; n < 4; ++n) {
      int gcol = col0 + wc * 64 + n * 16 + l15;
      float bv = bias[gcol];
#pragma unroll
      for (int r2 = 0; r2 < 4; ++r2)
        C[(size_t)(grow_b + r2) * N + gcol] = acc[m][n][r2] + bv;
    }
  }
}

// ---------------- RoPE + split + layout: qkv f32 -> Qb [B][H][S][D] (pre-scaled),
//                  Kb [B][HK][S][D], Vt [B][HK][D][S] (all bf16) ----------------
__global__ __launch_bounds__(256) void k_rope_split(const float* __restrict__ qkv,
                                                    const float* __restrict__ cosb,
                                                    const float* __restrict__ sinb,
                                                    u16* __restrict__ Qb, u16* __restrict__ Kb,
                                                    u16* __restrict__ Vt) {
  const int bs = blockIdx.x;
  const int b = bs >> 11, s = bs & 2047;
  const size_t base = (size_t)bs * NQKV_;
  const size_t cs = (size_t)bs * D_;
  const float qscale = 0.08838834764831845f;  // 1/sqrt(128)
  for (int p = threadIdx.x; p < H_ * 64; p += 256) {
    int h = p >> 6, d = p & 63;
    float f1 = qkv[base + h * D_ + d];
    float f2 = qkv[base + h * D_ + 64 + d];
    float c1 = cosb[cs + d], s1 = sinb[cs + d];
    float c2 = cosb[cs + 64 + d], s2 = sinb[cs + 64 + d];
    size_t o = ((size_t)(b * H_ + h) * S_ + s) * D_ + d;
    Qb[o] = f2bf((f1 * c1 - f2 * s1) * qscale);
    Qb[o + 64] = f2bf((f2 * c2 + f1 * s2) * qscale);
  }
  for (int p = threadIdx.x; p < HK_ * 64; p += 256) {
    int hk = p >> 6, d = p & 63;
    float f1 = qkv[base + H_ * D_ + hk * D_ + d];
    float f2 = qkv[base + H_ * D_ + hk * D_ + 64 + d];
    float c1 = cosb[cs + d], s1 = sinb[cs + d];
    float c2 = cosb[cs + 64 + d], s2 = sinb[cs + 64 + d];
    size_t o = ((size_t)(b * HK_ + hk) * S_ + s) * D_ + d;
    Kb[o] = f2bf(f1 * c1 - f2 * s1);
    Kb[o + 64] = f2bf(f2 * c2 + f1 * s2);
  }
  for (int p = threadIdx.x; p < HK_ * D_; p += 256) {
    int hk = p >> 7, d = p & 127;
    float v = qkv[base + H_ * D_ + HK_ * D_ + hk * D_ + d];
    Vt[((size_t)(b * HK_ + hk) * D_ + d) * S_ + s] = f2bf(v);
  }
}

// ---------------- flash attention: 64 q-rows/block, 4 waves x 16 rows ----------------
__global__ __launch_bounds__(256) void k_attn(const u16* __restrict__ Qb, const u16* __restrict__ Kb,
                                              const u16* __restrict__ Vt, u16* __restrict__ Ob) {
  __shared__ __attribute__((aligned(16))) u16 lK[64 * 128];   // [key][d], XOR-swizzled
  __shared__ __attribute__((aligned(16))) u16 lV[128 * 64];   // [d][key], XOR-swizzled
  __shared__ __attribute__((aligned(16))) u16 lP[4][16 * 72]; // per-wave P, padded rows
  const int qt = blockIdx.x;   // 0..31
  const int bh = blockIdx.y;   // 0..31
  const int b = bh >> 4, h = bh & 15;
  const int hk = h >> 2;
  const int tid = threadIdx.x, lane = tid & 63, wid = tid >> 6;
  const int l15 = lane & 15, l4 = lane >> 4;

  const int qrow = qt * 64 + wid * 16 + l15;
  const u16* qbase = Qb + ((size_t)(b * H_ + h) * S_ + qrow) * D_;
  bf16x8 qf[4];
#pragma unroll
  for (int ks = 0; ks < 4; ++ks) qf[ks] = *(const bf16x8*)(qbase + ks * 32 + l4 * 8);

  const u16* kbase = Kb + (size_t)(b * HK_ + hk) * S_ * D_;
  const u16* vbase = Vt + (size_t)(b * HK_ + hk) * D_ * S_;

  f32x4 o[8] = {};
  float mrun[4] = {-1e30f, -1e30f, -1e30f, -1e30f};
  float lrun[4] = {0.f, 0.f, 0.f, 0.f};

  char* lKc = (char*)lK;
  char* lVc = (char*)lV;
  u16* myP = &lP[wid][0];

  for (int kt = 0; kt < 32; ++kt) {
    // stage K tile [64][128] and V tile [128][64] (reg-staged, swizzled ds_write)
#pragma unroll
    for (int it = 0; it < 4; ++it) {
      int idx = it * 256 + tid;
      int kr = idx >> 4, c16 = idx & 15;
      bf16x8 kv = *(const bf16x8*)(kbase + (size_t)(kt * 64 + kr) * D_ + c16 * 8);
      *(bf16x8*)(lKc + ((kr * 256 + c16 * 16) ^ ((kr & 7) << 4))) = kv;
      int vr = idx >> 3, c8 = idx & 7;
      bf16x8 vv = *(const bf16x8*)(vbase + (size_t)vr * S_ + kt * 64 + c8 * 8);
      *(bf16x8*)(lVc + ((vr * 128 + c8 * 16) ^ ((vr & 7) << 4))) = vv;
    }
    __syncthreads();

    // scores: S[16 x 64] = Q(16x128) . K_tile^T
    f32x4 sc[4] = {};
#pragma unroll
    for (int ks = 0; ks < 4; ++ks) {
#pragma unroll
      for (int nf = 0; nf < 4; ++nf) {
        int kr = nf * 16 + l15;
        bf16x8 kf = *(const bf16x8*)(lKc + ((kr * 256 + ks * 64 + l4 * 16) ^ ((kr & 7) << 4)));
        sc[nf] = __builtin_amdgcn_mfma_f32_16x16x32_bf16(qf[ks], kf, sc[nf], 0, 0, 0);
      }
    }

    // online softmax (rows = l4*4+r, cols = nf*16+l15)
    float alpha[4];
#pragma unroll
    for (int r = 0; r < 4; ++r) {
      float m = fmaxf(fmaxf(sc[0][r], sc[1][r]), fmaxf(sc[2][r], sc[3][r]));
#pragma unroll
      for (int sh = 1; sh < 16; sh <<= 1) m = fmaxf(m, __shfl_xor(m, sh));
      float mn = fmaxf(mrun[r], m);
      alpha[r] = __expf(mrun[r] - mn);
      mrun[r] = mn;
      float rs = 0.f;
#pragma unroll
      for (int nf = 0; nf < 4; ++nf) {
        float p = __expf(sc[nf][r] - mn);
        sc[nf][r] = p;
        rs += p;
      }
#pragma unroll
      for (int sh = 1; sh < 16; sh <<= 1) rs += __shfl_xor(rs, sh);
      lrun[r] = lrun[r] * alpha[r] + rs;
    }
#pragma unroll
    for (int nf2 = 0; nf2 < 8; ++nf2)
#pragma unroll
      for (int r = 0; r < 4; ++r) o[nf2][r] *= alpha[r];

    // P -> LDS (C-layout write, A-frag read), padded row = 72 u16
#pragma unroll
    for (int r = 0; r < 4; ++r) {
      int prow = l4 * 4 + r;
#pragma unroll
      for (int nf = 0; nf < 4; ++nf)
        myP[prow * 72 + nf * 16 + l15] = f2bf(sc[nf][r]);
    }

    // PV: O += P(16x64) . V_tile(64x128)
#pragma unroll
    for (int ks2 = 0; ks2 < 2; ++ks2) {
      bf16x8 pf = *(const bf16x8*)((char*)myP + l15 * 144 + ks2 * 64 + l4 * 16);
#pragma unroll
      for (int nf2 = 0; nf2 < 8; ++nf2) {
        int dr = nf2 * 16 + l15;
        bf16x8 vf = *(const bf16x8*)(lVc + ((dr * 128 + ks2 * 64 + l4 * 16) ^ ((dr & 7) << 4)));
        o[nf2] = __builtin_amdgcn_mfma_f32_16x16x32_bf16(pf, vf, o[nf2], 0, 0, 0);
      }
    }
    __syncthreads();
  }

  // epilogue: attn_out [b][s][h*D+d] bf16
#pragma unroll
  for (int r = 0; r < 4; ++r) {
    int s = qt * 64 + wid * 16 + l4 * 4 + r;
    float inv = 1.0f / lrun[r];
    size_t ob = ((size_t)(b * S_ + s)) * HID_ + h * D_;
#pragma unroll
    for (int nf2 = 0; nf2 < 8; ++nf2)
      Ob[ob + nf2 * 16 + l15] = f2bf(o[nf2][r] * inv);
  }
}

extern "C" void kernel_launch(void* const* d_in, const int* in_sizes, int n_in,
                              void* d_out, int out_size, void* d_ws, size_t ws_size,
                              hipStream_t stream) {
  const float* hs = (const float*)d_in[0];
  const float* cosb = (const float*)d_in[1];
  const float* sinb = (const float*)d_in[2];
  const float* w_qkv = (const float*)d_in[3];
  const float* b_qkv = (const float*)d_in[4];
  const float* w_o = (const float*)d_in[5];
  const float* b_o = (const float*)d_in[6];
  float* out = (float*)d_out;

  char* ws = (char*)d_ws;
  u16* Xb    = (u16*)ws;                          // 16,777,216 B (reused as attn_out)
  u16* Wqkvb = (u16*)(ws + 16777216);             // 12,582,912 B
  u16* Wob   = (u16*)(ws + 29360128);             //  8,388,608 B
  float* qkv = (float*)(ws + 37748736);           // 50,331,648 B
  u16* Qb    = (u16*)(ws + 88080384);             // 16,777,216 B
  u16* Kb    = (u16*)(ws + 104857600);            //  4,194,304 B
  u16* Vt    = (u16*)(ws + 109051904);            //  4,194,304 B  (total 113,246,208 B)
  u16* Ob = Xb;

  hipLaunchKernelGGL(k_f32_to_bf16, dim3(2048), dim3(256), 0, stream, hs, Xb, (B_ * S_ * HID_) / 8);
  hipLaunchKernelGGL(k_f32_to_bf16, dim3(1536), dim3(256), 0, stream, w_qkv, Wqkvb, (NQKV_ * HID_) / 8);
  hipLaunchKernelGGL(k_f32_to_bf16, dim3(1024), dim3(256), 0, stream, w_o, Wob, (HID_ * HID_) / 8);
  hipLaunchKernelGGL(k_gemm_bt, dim3(NQKV_ / 128, (B_ * S_) / 128), dim3(256), 0, stream,
                     Xb, Wqkvb, b_qkv, qkv, B_ * S_, NQKV_, HID_);
  hipLaunchKernelGGL(k_rope_split, dim3(B_ * S_), dim3(256), 0, stream, qkv, cosb, sinb, Qb, Kb, Vt);
  hipLaunchKernelGGL(k_attn, dim3(S_ / 64, B_ * H_), dim3(256), 0, stream, Qb, Kb, Vt, Ob);
  hipLaunchKernelGGL(k_gemm_bt, dim3(HID_ / 128, (B_ * S_) / 128), dim3(256), 0, stream,
                     Ob, Wob, b_o, out, B_ * S_, HID_, HID_);
}